// Round 9
// baseline (404.328 us; speedup 1.0000x reference)
//
#include <hip/hip_runtime.h>
#include <hip/hip_bf16.h>
#include <math.h>

#define NB   16
#define NP   1024
#define KN   20
#define LN   10
#define NPT  16384   // NB*NP
#define NCLS 40

typedef short bf16x8 __attribute__((ext_vector_type(8)));
typedef float f32x4  __attribute__((ext_vector_type(4)));
typedef unsigned long long u64;

__device__ __forceinline__ short f2bf(float x) {
    __hip_bfloat16 h = __float2bfloat16(x);
    return *reinterpret_cast<short*>(&h);
}
__device__ __forceinline__ float bf2f(short s) {
    unsigned u = ((unsigned)(unsigned short)s) << 16;
    return __uint_as_float(u);
}
__device__ __forceinline__ unsigned pack2bf(float lo, float hi) {
    return (unsigned)(unsigned short)f2bf(lo) | ((unsigned)(unsigned short)f2bf(hi) << 16);
}

// ---------------------------------------------------------------------------
// Kernel 0: weight prep — W3 (18x256) -> W3T bf16 [256][32] (k zero-padded),
//           W4 (256x256) -> W4T bf16 [256][256]  (both [n][k] layout).
// ---------------------------------------------------------------------------
__global__ __launch_bounds__(256) void prep_k(const float* __restrict__ W3,
                                              const float* __restrict__ W4,
                                              short* __restrict__ W3T,
                                              short* __restrict__ W4T)
{
    const int k = blockIdx.x;    // 0..255
    const int n = threadIdx.x;   // 0..255
    W4T[n * 256 + k] = f2bf(W4[k * 256 + n]);
    if (k < 32) {
        float v = (k < 18) ? W3[k * 256 + n] : 0.0f;
        W3T[n * 32 + k] = f2bf(v);
    }
}

// ---------------------------------------------------------------------------
// Kernel 1: kNN. 16 scanner-lanes per center, 16 centers per block (256 thr).
// Grid = 1024 blocks. __launch_bounds__(256,2) keeps A[20]/merge in registers.
// u64 keys = (monotone d2 bits << 32)|idx -> exact top_k order.
// (Unchanged from R8 for attribution.)
// ---------------------------------------------------------------------------
__global__ __launch_bounds__(256, 2) void knn_k(const float* __restrict__ pos,
                                                int* __restrict__ nbr)
{
    __shared__ float4 sp[NP];            // 16 KB
    const int t    = threadIdx.x;
    const int blk  = blockIdx.x;         // 0..1023
    const int b    = blk >> 6;           // 64 blocks per batch
    const int base = b * NP;

    for (int i = t; i < NP; i += 256) {
        float x = pos[(base + i) * 3 + 0];
        float y = pos[(base + i) * 3 + 1];
        float z = pos[(base + i) * 3 + 2];
        sp[i] = make_float4(x, y, z, x * x + y * y + z * z);
    }
    __syncthreads();

    const int s    = t & 15;                       // scanner lane 0..15
    const int cLoc = (blk & 63) * 16 + (t >> 4);   // local center 0..1023
    const float4 cp = sp[cLoc];

    u64 A[20];
#pragma unroll
    for (int k = 0; k < 20; ++k) A[k] = ~0ull;

    const int q0 = s * 64;
    for (int ii = 0; ii < 64; ++ii) {
        int i = (ii + s) & 63;           // staggered scan order
        int q = q0 + i;
        float4 p = sp[q];
        float dot = cp.x * p.x + cp.y * p.y + cp.z * p.z;
        float d2  = (cp.w + p.w) - 2.0f * dot;
        unsigned u = __float_as_uint(d2);
        u ^= (unsigned)(((int)u >> 31) | 0x80000000);   // monotone map
        u64 key = ((u64)u << 32) | (unsigned)q;
        if (q == cLoc) key = ~0ull;                     // self-exclusion
        if (key < A[19]) {
            A[19] = key;
#pragma unroll
            for (int j = 19; j > 0; --j)
                if (A[j] < A[j - 1]) { u64 tmp = A[j]; A[j] = A[j - 1]; A[j - 1] = tmp; }
        }
    }

    // 4-level merge tree across scanner lanes (1,2,4,8).
#pragma unroll
    for (int m = 1; m <= 8; m <<= 1) {
        u64 Bv[20];
#pragma unroll
        for (int k = 0; k < 20; ++k) Bv[k] = __shfl_xor(A[k], m);
        u64 L[32];
#pragma unroll
        for (int i = 0; i < 12; ++i) L[i] = A[i];
#pragma unroll
        for (int i = 12; i < 20; ++i) L[i] = (A[i] < Bv[31 - i]) ? A[i] : Bv[31 - i];
#pragma unroll
        for (int i = 20; i < 32; ++i) L[i] = Bv[31 - i];
#pragma unroll
        for (int d = 16; d >= 1; d >>= 1)
#pragma unroll
            for (int i = 0; i < 32; ++i)
                if ((i & d) == 0) {
                    u64 lo = (L[i] < L[i + d]) ? L[i] : L[i + d];
                    u64 hi = (L[i] < L[i + d]) ? L[i + d] : L[i];
                    L[i] = lo; L[i + d] = hi;
                }
#pragma unroll
        for (int k = 0; k < 20; ++k) A[k] = L[k];
    }

    if (s == 0) {
        const int n = base + cLoc;
#pragma unroll
        for (int k = 0; k < 20; ++k)
            nbr[n * KN + k] = base + (int)(unsigned)(A[k] & 0xFFFFFFFFull);
    }
}

// ---------------------------------------------------------------------------
// Jacobi rotation (matches reference math incl. nz / sign(0)=0 semantics).
// ---------------------------------------------------------------------------
__device__ __forceinline__ void jrot(float& app, float& aqq, float& apq,
                                     float& apr, float& aqr,
                                     float& vp0, float& vp1, float& vp2,
                                     float& vq0, float& vq1, float& vq2)
{
    bool  nz    = fabsf(apq) > 1e-12f;
    float denom = nz ? 2.0f * apq : 1.0f;
    float tau   = (aqq - app) / denom;
    float sg    = (tau > 0.0f) ? 1.0f : ((tau < 0.0f) ? -1.0f : 0.0f);
    float t     = nz ? sg / (fabsf(tau) + sqrtf(1.0f + tau * tau)) : 0.0f;
    float c     = 1.0f / sqrtf(1.0f + t * t);
    float s     = t * c;

    float app_n = c * c * app - 2.0f * c * s * apq + s * s * aqq;
    float aqq_n = s * s * app + 2.0f * c * s * apq + c * c * aqq;
    float apq_n = c * s * (app - aqq) + (c * c - s * s) * apq;
    float apr_n = c * apr - s * aqr;
    float aqr_n = s * apr + c * aqr;
    app = app_n; aqq = aqq_n; apq = apq_n; apr = apr_n; aqr = aqr_n;

    float t0;
    t0 = c * vp0 - s * vq0; vq0 = s * vp0 + c * vq0; vp0 = t0;
    t0 = c * vp1 - s * vq1; vq1 = s * vp1 + c * vq1; vp1 = t0;
    t0 = c * vp2 - s * vq2; vq2 = s * vp2 + c * vq2; vp2 = t0;
}

// ---------------------------------------------------------------------------
// Kernel 2: per-point geometry. Block=64, grid=256. featO bf16. (Unchanged.)
// ---------------------------------------------------------------------------
__global__ __launch_bounds__(64) void geom_k(const float* __restrict__ pos,
                                             const int* __restrict__ nbr,
                                             const float* __restrict__ W1,
                                             const float* __restrict__ b1,
                                             const float* __restrict__ W2,
                                             const float* __restrict__ b2,
                                             float* __restrict__ dirc,
                                             short* __restrict__ featO,
                                             float* __restrict__ Vg)
{
    __shared__ float sW1[96], sb1[32], sb2[15], sW2[480];
    const int tid = threadIdx.x;
    for (int i = tid; i < 96;  i += 64) sW1[i] = W1[i];
    if (tid < 32) sb1[tid] = b1[tid];
    for (int i = tid; i < 480; i += 64) sW2[i] = W2[i];
    if (tid < 15) sb2[tid] = b2[tid];
    __syncthreads();

    const int n = blockIdx.x * 64 + tid;
    const float px = pos[n * 3 + 0], py = pos[n * 3 + 1], pz = pos[n * 3 + 2];

    float cl[KN][3];
#pragma unroll
    for (int k = 0; k < KN; ++k) {
        int j = nbr[n * KN + k];
        cl[k][0] = pos[j * 3 + 0] - px;
        cl[k][1] = pos[j * 3 + 1] - py;
        cl[k][2] = pos[j * 3 + 2] - pz;
    }

    float a00 = 0, a01 = 0, a02 = 0, a11 = 0, a12 = 0, a22 = 0;
#pragma unroll
    for (int k = 0; k < LN; ++k) {
        a00 += cl[k][0] * cl[k][0]; a01 += cl[k][0] * cl[k][1]; a02 += cl[k][0] * cl[k][2];
        a11 += cl[k][1] * cl[k][1]; a12 += cl[k][1] * cl[k][2]; a22 += cl[k][2] * cl[k][2];
    }

    float v00 = 1, v01 = 0, v02 = 0,
          v10 = 0, v11 = 1, v12 = 0,
          v20 = 0, v21 = 0, v22 = 1;
#pragma unroll
    for (int it = 0; it < 5; ++it) {
        jrot(a00, a11, a01, a02, a12, v00, v10, v20, v01, v11, v21);
        jrot(a00, a22, a02, a01, a12, v00, v10, v20, v02, v12, v22);
        jrot(a11, a22, a12, a01, a02, v01, v11, v21, v02, v12, v22);
    }

    float s2 = 0.0f;
#pragma unroll
    for (int k = 0; k < KN; ++k) {
        float d0 = cl[k][0] * v00 + cl[k][1] * v10 + cl[k][2] * v20;
        float d1 = cl[k][0] * v01 + cl[k][1] * v11 + cl[k][2] * v21;
        float d2 = cl[k][0] * v02 + cl[k][1] * v12 + cl[k][2] * v22;
        cl[k][0] = d0; cl[k][1] = d1; cl[k][2] = d2;
        s2 += d2;
    }
    float sg = (s2 > 0.0f) ? 1.0f : ((s2 < 0.0f) ? -1.0f : 0.0f);

#pragma unroll
    for (int k = 0; k < KN; ++k) {
        cl[k][2] *= sg;
        dirc[n * 60 + k * 3 + 0] = cl[k][0];
        dirc[n * 60 + k * 3 + 1] = cl[k][1];
        dirc[n * 60 + k * 3 + 2] = cl[k][2];
    }

    float hs[32];
#pragma unroll
    for (int c = 0; c < 32; ++c) {
        float w0 = sW1[c], w1 = sW1[32 + c], w2 = sW1[64 + c], bb = sb1[c];
        float acc = 0.0f;
#pragma unroll
        for (int k = 0; k < KN; ++k)
            acc += fmaxf(bb + cl[k][0] * w0 + cl[k][1] * w1 + cl[k][2] * w2, 0.0f);
        hs[c] = acc;
    }

    Vg[n * 9 + 0] = v00; Vg[n * 9 + 1] = v10; Vg[n * 9 + 2] = v20;
    Vg[n * 9 + 3] = v01; Vg[n * 9 + 4] = v11; Vg[n * 9 + 5] = v21;
    Vg[n * 9 + 6] = v02; Vg[n * 9 + 7] = v12; Vg[n * 9 + 8] = v22;

#pragma unroll
    for (int j = 0; j < 15; ++j) {
        float x = 20.0f * sb2[j];
#pragma unroll
        for (int c = 0; c < 32; ++c) x += hs[c] * sW2[c * 15 + j];
        featO[n * 15 + j] = f2bf(1.0f / (1.0f + expf(-x)));
    }
}

// ---------------------------------------------------------------------------
// Kernel 3: per-edge MLP via MFMA. One block (4 waves) per 3 POINTS.
// R9: nbr_s barrier removed (sfeat stage reads nbr[pt0*20+nb] directly);
// epilogue atomicAdds per-point sums into ysum[batch][256] (psum_k deleted,
// 16.7MB pf HBM round-trip eliminated). 3 barriers total.
// ---------------------------------------------------------------------------
__global__ __launch_bounds__(256, 4) void mlp_k(const int* __restrict__ nbr,
                                                const float* __restrict__ dirc,
                                                const short* __restrict__ featB,
                                                const float* __restrict__ Vg,
                                                const short* __restrict__ W3T,
                                                const float* __restrict__ b3,
                                                const short* __restrict__ W4T,
                                                const float* __restrict__ b4,
                                                float* __restrict__ ysum)
{
    __shared__ __align__(16) short H1L[64 * 256];    // 32,768 B, XOR-swizzled
    __shared__ __align__(16) short concatL[64 * 40]; //  5,120 B (stride 40)
    __shared__ short sfeatS[60 * 16];                //  1,920 B (stride 16)
    __shared__ float Vr_s[27];

    const int t   = threadIdx.x;
    const int l   = t & 63;
    const int lg  = l >> 4;            // lane group 0..3
    const int lc  = l & 15;            // lane col 0..15
    const int n0w = (t >> 6) * 64;     // wave's dim-slice base
    const int pt0 = blockIdx.x * 3;    // first point of this block
    const int swz = (lc & 7) << 3;     // short-index XOR = byte ^((row&7)<<4)

    if (t >= 64 && t < 91) {
        int e = t - 64;                // p*9 + j
        int pt = pt0 + e / 9;
        Vr_s[e] = (pt < NPT) ? Vg[pt * 9 + (e % 9)] : 0.0f;
    }
    for (int i = t; i < 1280; i += 256) ((int*)concatL)[i] = 0;

    // Stage neighbor feats (60 x 15 bf16) into LDS; nbr read directly:
    // neighbor nb of block = nbr[(pt0+nb/20)*20 + nb%20] == nbr[pt0*20 + nb]
    for (int i2 = t; i2 < 900; i2 += 256) {
        int nb = i2 / 15, c = i2 - nb * 15;
        int gi = pt0 * 20 + nb;
        int idx = (gi < NPT * 20) ? nbr[gi] : 0;
        sfeatS[nb * 16 + c] = featB[idx * 15 + c];
    }
    __syncthreads();

    // Phase A: concat rows (3 points x 20 edges x 18 cols), bf16 in LDS
    for (int job = t; job < 1080; job += 256) {
        int p  = job / 360;
        int rr = job - p * 360;
        int k  = rr / 18;
        int c  = rr - k * 18;
        int pt = pt0 + p;
        float val = 0.0f;
        if (pt < NPT) {
            if (c < 3) {
                val = dirc[pt * 60 + k * 3 + c];
            } else {
                int e = c - 3, g = e / 3, i = e - g * 3;
                const short* fr = &sfeatS[(p * 20 + k) * 16 + g * 3];
                const float* Vr = Vr_s + p * 9;
                val = bf2f(fr[0]) * Vr[i * 3 + 0] + bf2f(fr[1]) * Vr[i * 3 + 1] + bf2f(fr[2]) * Vr[i * 3 + 2];
            }
        }
        concatL[(p * 20 + k) * 40 + c] = f2bf(val);
    }
    __syncthreads();

    // Phase B (swapped): H1[row][dim] = relu(concat[row]·W3[:,dim] + b3[dim])
    {
        f32x4 accB[4][4];                 // [mt: dim-tile][nt: row-tile]
#pragma unroll
        for (int mt = 0; mt < 4; ++mt)
#pragma unroll
            for (int nt = 0; nt < 4; ++nt)
#pragma unroll
                for (int r = 0; r < 4; ++r) accB[mt][nt][r] = 0.0f;

        bf16x8 aB[4], bB[4];
#pragma unroll
        for (int nt = 0; nt < 4; ++nt)    // concat fragments (per row-tile)
            aB[nt] = *(const bf16x8*)&concatL[(nt * 16 + lc) * 40 + lg * 8];
#pragma unroll
        for (int mt = 0; mt < 4; ++mt)    // W3T fragments (per dim-tile)
            bB[mt] = *(const bf16x8*)&W3T[(n0w + mt * 16 + lc) * 32 + lg * 8];
#pragma unroll
        for (int mt = 0; mt < 4; ++mt)
#pragma unroll
            for (int nt = 0; nt < 4; ++nt)
                accB[mt][nt] = __builtin_amdgcn_mfma_f32_16x16x32_bf16(bB[mt], aB[nt], accB[mt][nt], 0, 0, 0);

        // lane holds H1[row = nt*16+lc][dim = n0w + mt*16 + lg*4 + r], r=0..3
#pragma unroll
        for (int mt = 0; mt < 4; ++mt) {
            const int dim0 = n0w + mt * 16 + lg * 4;
            const float4 b3q = *(const float4*)&b3[dim0];
#pragma unroll
            for (int nt = 0; nt < 4; ++nt) {
                const int row = nt * 16 + lc;
                uint2 w;
                w.x = pack2bf(fmaxf(accB[mt][nt][0] + b3q.x, 0.0f),
                              fmaxf(accB[mt][nt][1] + b3q.y, 0.0f));
                w.y = pack2bf(fmaxf(accB[mt][nt][2] + b3q.z, 0.0f),
                              fmaxf(accB[mt][nt][3] + b3q.w, 0.0f));
                *reinterpret_cast<uint2*>(&H1L[row * 256 + (dim0 ^ swz)]) = w;
            }
        }
    }
    __syncthreads();

    // Phase C: h2 = H1 @ W4 over 8 K-chunks of 32
    f32x4 acc[4][4];
#pragma unroll
    for (int mt = 0; mt < 4; ++mt)
#pragma unroll
        for (int nt = 0; nt < 4; ++nt)
#pragma unroll
            for (int r = 0; r < 4; ++r) acc[mt][nt][r] = 0.0f;

#pragma unroll
    for (int ch = 0; ch < 8; ++ch) {
        bf16x8 a[4], b[4];
#pragma unroll
        for (int mt = 0; mt < 4; ++mt)    // H1 A-frag: row mt*16+lc, k-dims
            a[mt] = *(const bf16x8*)&H1L[(mt * 16 + lc) * 256 + ((ch * 32 + lg * 8) ^ swz)];
#pragma unroll
        for (int nt = 0; nt < 4; ++nt)
            b[nt] = *(const bf16x8*)&W4T[(n0w + nt * 16 + lc) * 256 + ch * 32 + lg * 8];
#pragma unroll
        for (int mt = 0; mt < 4; ++mt)
#pragma unroll
            for (int nt = 0; nt < 4; ++nt)
                acc[mt][nt] = __builtin_amdgcn_mfma_f32_16x16x32_bf16(a[mt], b[nt], acc[mt][nt], 0, 0, 0);
    }

    // Epilogue: relu(+b4), per-point sums via compile-time lane-group masks,
    // then atomicAdd into ysum[batch][col] (replaces pf + psum_k).
    const float m1 = (lg == 0) ? 1.0f : 0.0f;
    const float m2 = (lg <  2) ? 1.0f : 0.0f;
    const float m3 = (lg <  3) ? 1.0f : 0.0f;
    const int v0 = (pt0 + 0) < NPT, v1 = (pt0 + 1) < NPT, v2 = (pt0 + 2) < NPT;
    const int b0 = (pt0 + 0) >> 10, b1v = (pt0 + 1) >> 10, b2v = (pt0 + 2) >> 10;
#pragma unroll
    for (int nt = 0; nt < 4; ++nt) {
        int col = n0w + nt * 16 + lc;
        float b4v = b4[col];
        float a0 = 0.0f, a1 = 0.0f, a2 = 0.0f, a3 = 0.0f;
#pragma unroll
        for (int r = 0; r < 4; ++r) {
            a0 += fmaxf(acc[0][nt][r] + b4v, 0.0f);
            a1 += fmaxf(acc[1][nt][r] + b4v, 0.0f);
            a2 += fmaxf(acc[2][nt][r] + b4v, 0.0f);
            a3 += fmaxf(acc[3][nt][r] + b4v, 0.0f);
        }
        float s0 = a0 + m1 * a1;
        float s1 = (1.0f - m1) * a1 + m2 * a2;
        float s2 = (1.0f - m2) * a2 + m3 * a3;
        s0 += __shfl_xor(s0, 16); s0 += __shfl_xor(s0, 32);
        s1 += __shfl_xor(s1, 16); s1 += __shfl_xor(s1, 32);
        s2 += __shfl_xor(s2, 16); s2 += __shfl_xor(s2, 32);
        if (l < 16) {
            if (v0) atomicAdd(&ysum[b0 * 256 + col], s0);
            if (v1) atomicAdd(&ysum[b1v * 256 + col], s1);
            if (v2) atomicAdd(&ysum[b2v * 256 + col], s2);
        }
    }
}

// ---------------------------------------------------------------------------
// Kernel 4: head (16 blocks) — reads ysum directly.
// ---------------------------------------------------------------------------
__global__ __launch_bounds__(256) void head2_k(const float* __restrict__ ysum,
                                               const float* __restrict__ Wn1,
                                               const float* __restrict__ bn1,
                                               const float* __restrict__ Wn2,
                                               const float* __restrict__ bn2,
                                               float* __restrict__ out)
{
    __shared__ float ysh[256], y1h[256], zsh[64];
    const int t = threadIdx.x, b = blockIdx.x;

    ysh[t] = ysum[b * 256 + t] * (1.0f / 1024.0f);
    __syncthreads();

    float acc = bn1[t];
    for (int c = 0; c < 256; ++c) acc += ysh[c] * Wn1[c * 256 + t];
    y1h[t] = (acc > 0.0f) ? acc : expm1f(acc);
    __syncthreads();

    if (t < NCLS) {
        float z = bn2[t];
        for (int c = 0; c < 256; ++c) z += y1h[c] * Wn2[c * NCLS + t];
        zsh[t] = z;
    }
    __syncthreads();

    if (t < 64) {
        float v = (t < NCLS) ? zsh[t] : -3.0e38f;
        float m = v;
#pragma unroll
        for (int off = 32; off >= 1; off >>= 1) m = fmaxf(m, __shfl_xor(m, off));
        float e = (t < NCLS) ? expf(zsh[t] - m) : 0.0f;
#pragma unroll
        for (int off = 32; off >= 1; off >>= 1) e += __shfl_xor(e, off);
        if (t < NCLS) out[b * NCLS + t] = zsh[t] - m - logf(e);
    }
}

// ---------------------------------------------------------------------------
extern "C" void kernel_launch(void* const* d_in, const int* in_sizes, int n_in,
                              void* d_out, int out_size, void* d_ws, size_t ws_size,
                              hipStream_t stream)
{
    const float* pos = (const float*)d_in[0];
    const float* W1  = (const float*)d_in[1];
    const float* b1  = (const float*)d_in[2];
    const float* W2  = (const float*)d_in[3];
    const float* b2  = (const float*)d_in[4];
    const float* W3  = (const float*)d_in[5];
    const float* b3  = (const float*)d_in[6];
    const float* W4  = (const float*)d_in[7];
    const float* b4  = (const float*)d_in[8];
    const float* Wn1 = (const float*)d_in[9];
    const float* bn1 = (const float*)d_in[10];
    const float* Wn2 = (const float*)d_in[11];
    const float* bn2 = (const float*)d_in[12];
    float* out = (float*)d_out;

    char* ws = (char*)d_ws;
    // workspace layout (bytes), all 256B aligned
    int*   nbr  = (int*)(ws + 0);              // 1,310,720
    float* dirc = (float*)(ws + 1310720);      // 3,932,160 -> ends 5,242,880
    short* feat = (short*)(ws + 5242880);      //   491,520 -> ends 5,734,400 (bf16)
    float* Vg   = (float*)(ws + 5734400);      //   589,824 -> ends 6,324,224
    float* ysum = (float*)(ws + 6324224);      //    16,384 -> ends 6,340,608
    short* W4T  = (short*)(ws + 6340608);      //   131,072 -> ends 6,471,680
    short* W3T  = (short*)(ws + 6471680);      //    16,384 -> ends 6,488,064

    hipMemsetAsync(ysum, 0, NB * 256 * sizeof(float), stream);
    prep_k <<<256,            256, 0, stream>>>(W3, W4, W3T, W4T);
    knn_k  <<<1024,           256, 0, stream>>>(pos, nbr);
    geom_k <<<256,             64, 0, stream>>>(pos, nbr, W1, b1, W2, b2, dirc, feat, Vg);
    mlp_k  <<<(NPT + 2) / 3,  256, 0, stream>>>(nbr, dirc, feat, Vg, W3T, b3, W4T, b4, ysum);
    head2_k<<<NB,             256, 0, stream>>>(ysum, Wn1, bn1, Wn2, bn2, out);
}

// Round 10
// 311.331 us; speedup vs baseline: 1.2987x; 1.2987x over previous
//
#include <hip/hip_runtime.h>
#include <hip/hip_bf16.h>
#include <math.h>

#define NB   16
#define NP   1024
#define KN   20
#define LN   10
#define NPT  16384   // NB*NP
#define NCLS 40

typedef short bf16x8 __attribute__((ext_vector_type(8)));
typedef float f32x4  __attribute__((ext_vector_type(4)));

__device__ __forceinline__ short f2bf(float x) {
    __hip_bfloat16 h = __float2bfloat16(x);
    return *reinterpret_cast<short*>(&h);
}
__device__ __forceinline__ float bf2f(short s) {
    unsigned u = ((unsigned)(unsigned short)s) << 16;
    return __uint_as_float(u);
}
__device__ __forceinline__ unsigned pack2bf(float lo, float hi) {
    return (unsigned)(unsigned short)f2bf(lo) | ((unsigned)(unsigned short)f2bf(hi) << 16);
}
__device__ __forceinline__ unsigned umn(unsigned a, unsigned b) { return a < b ? a : b; }
__device__ __forceinline__ unsigned umx(unsigned a, unsigned b) { return a < b ? b : a; }

// ---------------------------------------------------------------------------
// Kernel 0: weight prep — W3 (18x256) -> W3T bf16 [256][32] (k zero-padded),
//           W4 (256x256) -> W4T bf16 [256][256]  (both [n][k] layout).
// ---------------------------------------------------------------------------
__global__ __launch_bounds__(256) void prep_k(const float* __restrict__ W3,
                                              const float* __restrict__ W4,
                                              short* __restrict__ W3T,
                                              short* __restrict__ W4T)
{
    const int k = blockIdx.x;    // 0..255
    const int n = threadIdx.x;   // 0..255
    W4T[n * 256 + k] = f2bf(W4[k * 256 + n]);
    if (k < 32) {
        float v = (k < 18) ? W3[k * 256 + n] : 0.0f;
        W3T[n * 32 + k] = f2bf(v);
    }
}

// ---------------------------------------------------------------------------
// Kernel 1: kNN, u32 packed keys. 16 scanner-lanes per center, 16 centers per
// block. key = (monotone_d2_bits & ~1023) | idx  — single u32 per candidate:
// insertion bubble + bitonic merge become v_min_u32/v_max_u32 pairs (~3x
// fewer VALU ops than the u64 version). Only neighbor SETS matter downstream
// (cov uses 10 nearest; all other uses are k-sums), so 22-bit d2 + idx
// tiebreak deviates from exact top_k only on near-exact ties.
// ---------------------------------------------------------------------------
__global__ __launch_bounds__(256, 2) void knn_k(const float* __restrict__ pos,
                                                int* __restrict__ nbr)
{
    __shared__ float4 sp[NP];            // 16 KB
    const int t    = threadIdx.x;
    const int blk  = blockIdx.x;         // 0..1023
    const int b    = blk >> 6;           // 64 blocks per batch
    const int base = b * NP;

    for (int i = t; i < NP; i += 256) {
        float x = pos[(base + i) * 3 + 0];
        float y = pos[(base + i) * 3 + 1];
        float z = pos[(base + i) * 3 + 2];
        sp[i] = make_float4(x, y, z, x * x + y * y + z * z);
    }
    __syncthreads();

    const int s    = t & 15;                       // scanner lane 0..15
    const int cLoc = (blk & 63) * 16 + (t >> 4);   // local center 0..1023
    const float4 cp = sp[cLoc];

    unsigned A[20];
#pragma unroll
    for (int k = 0; k < 20; ++k) A[k] = 0xFFFFFFFFu;

    const int q0 = s * 64;
    for (int ii = 0; ii < 64; ++ii) {
        int i = (ii + s) & 63;           // staggered scan order
        int q = q0 + i;
        float4 p = sp[q];
        float dot = cp.x * p.x + cp.y * p.y + cp.z * p.z;
        float d2  = (cp.w + p.w) - 2.0f * dot;
        unsigned u = __float_as_uint(d2);
        u ^= (unsigned)(((int)u >> 31) | 0x80000000);   // monotone map
        unsigned key = (u & 0xFFFFFC00u) | (unsigned)q; // 22b d2 | 10b idx
        if (q == cLoc) key = 0xFFFFFFFFu;               // self-exclusion
        if (key < A[19]) {
            A[19] = key;
#pragma unroll
            for (int j = 19; j > 0; --j) {
                unsigned lo = umn(A[j], A[j - 1]), hi = umx(A[j], A[j - 1]);
                A[j - 1] = lo; A[j] = hi;
            }
        }
    }

    // 4-level merge tree across scanner lanes (1,2,4,8).
#pragma unroll
    for (int m = 1; m <= 8; m <<= 1) {
        unsigned Bv[20];
#pragma unroll
        for (int k = 0; k < 20; ++k) Bv[k] = __shfl_xor(A[k], m);
        unsigned L[32];
#pragma unroll
        for (int i = 0; i < 12; ++i) L[i] = A[i];               // min(A[i], MAX)
#pragma unroll
        for (int i = 12; i < 20; ++i) L[i] = umn(A[i], Bv[31 - i]);
#pragma unroll
        for (int i = 20; i < 32; ++i) L[i] = Bv[31 - i];        // min(MAX, B)
        // L is bitonic; clean-sort it (min/max network).
#pragma unroll
        for (int d = 16; d >= 1; d >>= 1)
#pragma unroll
            for (int i = 0; i < 32; ++i)
                if ((i & d) == 0) {
                    unsigned lo = umn(L[i], L[i + d]), hi = umx(L[i], L[i + d]);
                    L[i] = lo; L[i + d] = hi;
                }
#pragma unroll
        for (int k = 0; k < 20; ++k) A[k] = L[k];
    }

    if (s == 0) {
        const int n = base + cLoc;
#pragma unroll
        for (int k = 0; k < 20; ++k)
            nbr[n * KN + k] = base + (int)(A[k] & 1023u);
    }
}

// ---------------------------------------------------------------------------
// Jacobi rotation (matches reference math incl. nz / sign(0)=0 semantics).
// ---------------------------------------------------------------------------
__device__ __forceinline__ void jrot(float& app, float& aqq, float& apq,
                                     float& apr, float& aqr,
                                     float& vp0, float& vp1, float& vp2,
                                     float& vq0, float& vq1, float& vq2)
{
    bool  nz    = fabsf(apq) > 1e-12f;
    float denom = nz ? 2.0f * apq : 1.0f;
    float tau   = (aqq - app) / denom;
    float sg    = (tau > 0.0f) ? 1.0f : ((tau < 0.0f) ? -1.0f : 0.0f);
    float t     = nz ? sg / (fabsf(tau) + sqrtf(1.0f + tau * tau)) : 0.0f;
    float c     = 1.0f / sqrtf(1.0f + t * t);
    float s     = t * c;

    float app_n = c * c * app - 2.0f * c * s * apq + s * s * aqq;
    float aqq_n = s * s * app + 2.0f * c * s * apq + c * c * aqq;
    float apq_n = c * s * (app - aqq) + (c * c - s * s) * apq;
    float apr_n = c * apr - s * aqr;
    float aqr_n = s * apr + c * aqr;
    app = app_n; aqq = aqq_n; apq = apq_n; apr = apr_n; aqr = aqr_n;

    float t0;
    t0 = c * vp0 - s * vq0; vq0 = s * vp0 + c * vq0; vp0 = t0;
    t0 = c * vp1 - s * vq1; vq1 = s * vp1 + c * vq1; vp1 = t0;
    t0 = c * vp2 - s * vq2; vq2 = s * vp2 + c * vq2; vp2 = t0;
}

// ---------------------------------------------------------------------------
// Kernel 2: per-point geometry. Block=64, grid=256. featO bf16. (Unchanged.)
// ---------------------------------------------------------------------------
__global__ __launch_bounds__(64) void geom_k(const float* __restrict__ pos,
                                             const int* __restrict__ nbr,
                                             const float* __restrict__ W1,
                                             const float* __restrict__ b1,
                                             const float* __restrict__ W2,
                                             const float* __restrict__ b2,
                                             float* __restrict__ dirc,
                                             short* __restrict__ featO,
                                             float* __restrict__ Vg)
{
    __shared__ float sW1[96], sb1[32], sb2[15], sW2[480];
    const int tid = threadIdx.x;
    for (int i = tid; i < 96;  i += 64) sW1[i] = W1[i];
    if (tid < 32) sb1[tid] = b1[tid];
    for (int i = tid; i < 480; i += 64) sW2[i] = W2[i];
    if (tid < 15) sb2[tid] = b2[tid];
    __syncthreads();

    const int n = blockIdx.x * 64 + tid;
    const float px = pos[n * 3 + 0], py = pos[n * 3 + 1], pz = pos[n * 3 + 2];

    float cl[KN][3];
#pragma unroll
    for (int k = 0; k < KN; ++k) {
        int j = nbr[n * KN + k];
        cl[k][0] = pos[j * 3 + 0] - px;
        cl[k][1] = pos[j * 3 + 1] - py;
        cl[k][2] = pos[j * 3 + 2] - pz;
    }

    float a00 = 0, a01 = 0, a02 = 0, a11 = 0, a12 = 0, a22 = 0;
#pragma unroll
    for (int k = 0; k < LN; ++k) {
        a00 += cl[k][0] * cl[k][0]; a01 += cl[k][0] * cl[k][1]; a02 += cl[k][0] * cl[k][2];
        a11 += cl[k][1] * cl[k][1]; a12 += cl[k][1] * cl[k][2]; a22 += cl[k][2] * cl[k][2];
    }

    float v00 = 1, v01 = 0, v02 = 0,
          v10 = 0, v11 = 1, v12 = 0,
          v20 = 0, v21 = 0, v22 = 1;
#pragma unroll
    for (int it = 0; it < 5; ++it) {
        jrot(a00, a11, a01, a02, a12, v00, v10, v20, v01, v11, v21);
        jrot(a00, a22, a02, a01, a12, v00, v10, v20, v02, v12, v22);
        jrot(a11, a22, a12, a01, a02, v01, v11, v21, v02, v12, v22);
    }

    float s2 = 0.0f;
#pragma unroll
    for (int k = 0; k < KN; ++k) {
        float d0 = cl[k][0] * v00 + cl[k][1] * v10 + cl[k][2] * v20;
        float d1 = cl[k][0] * v01 + cl[k][1] * v11 + cl[k][2] * v21;
        float d2 = cl[k][0] * v02 + cl[k][1] * v12 + cl[k][2] * v22;
        cl[k][0] = d0; cl[k][1] = d1; cl[k][2] = d2;
        s2 += d2;
    }
    float sg = (s2 > 0.0f) ? 1.0f : ((s2 < 0.0f) ? -1.0f : 0.0f);

#pragma unroll
    for (int k = 0; k < KN; ++k) {
        cl[k][2] *= sg;
        dirc[n * 60 + k * 3 + 0] = cl[k][0];
        dirc[n * 60 + k * 3 + 1] = cl[k][1];
        dirc[n * 60 + k * 3 + 2] = cl[k][2];
    }

    float hs[32];
#pragma unroll
    for (int c = 0; c < 32; ++c) {
        float w0 = sW1[c], w1 = sW1[32 + c], w2 = sW1[64 + c], bb = sb1[c];
        float acc = 0.0f;
#pragma unroll
        for (int k = 0; k < KN; ++k)
            acc += fmaxf(bb + cl[k][0] * w0 + cl[k][1] * w1 + cl[k][2] * w2, 0.0f);
        hs[c] = acc;
    }

    Vg[n * 9 + 0] = v00; Vg[n * 9 + 1] = v10; Vg[n * 9 + 2] = v20;
    Vg[n * 9 + 3] = v01; Vg[n * 9 + 4] = v11; Vg[n * 9 + 5] = v21;
    Vg[n * 9 + 6] = v02; Vg[n * 9 + 7] = v12; Vg[n * 9 + 8] = v22;

#pragma unroll
    for (int j = 0; j < 15; ++j) {
        float x = 20.0f * sb2[j];
#pragma unroll
        for (int c = 0; c < 32; ++c) x += hs[c] * sW2[c * 15 + j];
        featO[n * 15 + j] = f2bf(1.0f / (1.0f + expf(-x)));
    }
}

// ---------------------------------------------------------------------------
// Kernel 3: per-edge MLP via MFMA. One block (4 waves) per 3 POINTS.
// R10: pf-store epilogue (R8) restored — the R9 far-atomic fusion serialized
// at the cross-XCD coherence point (WRITE_SIZE stayed 16MB, +50µs). Keeps
// R9's barrier removal (nbr read directly in sfeat staging; 3 barriers).
// ---------------------------------------------------------------------------
__global__ __launch_bounds__(256, 4) void mlp_k(const int* __restrict__ nbr,
                                                const float* __restrict__ dirc,
                                                const short* __restrict__ featB,
                                                const float* __restrict__ Vg,
                                                const short* __restrict__ W3T,
                                                const float* __restrict__ b3,
                                                const short* __restrict__ W4T,
                                                const float* __restrict__ b4,
                                                float* __restrict__ pf)
{
    __shared__ __align__(16) short H1L[64 * 256];    // 32,768 B, XOR-swizzled
    __shared__ __align__(16) short concatL[64 * 40]; //  5,120 B (stride 40)
    __shared__ short sfeatS[60 * 16];                //  1,920 B (stride 16)
    __shared__ float Vr_s[27];

    const int t   = threadIdx.x;
    const int l   = t & 63;
    const int lg  = l >> 4;            // lane group 0..3
    const int lc  = l & 15;            // lane col 0..15
    const int n0w = (t >> 6) * 64;     // wave's dim-slice base
    const int pt0 = blockIdx.x * 3;    // first point of this block
    const int swz = (lc & 7) << 3;     // short-index XOR = byte ^((row&7)<<4)

    if (t >= 64 && t < 91) {
        int e = t - 64;                // p*9 + j
        int pt = pt0 + e / 9;
        Vr_s[e] = (pt < NPT) ? Vg[pt * 9 + (e % 9)] : 0.0f;
    }
    for (int i = t; i < 1280; i += 256) ((int*)concatL)[i] = 0;

    // Stage neighbor feats (60 x 15 bf16): nbr[(pt0+nb/20)*20+nb%20]==nbr[pt0*20+nb]
    for (int i2 = t; i2 < 900; i2 += 256) {
        int nb = i2 / 15, c = i2 - nb * 15;
        int gi = pt0 * 20 + nb;
        int idx = (gi < NPT * 20) ? nbr[gi] : 0;
        sfeatS[nb * 16 + c] = featB[idx * 15 + c];
    }
    __syncthreads();

    // Phase A: concat rows (3 points x 20 edges x 18 cols), bf16 in LDS
    for (int job = t; job < 1080; job += 256) {
        int p  = job / 360;
        int rr = job - p * 360;
        int k  = rr / 18;
        int c  = rr - k * 18;
        int pt = pt0 + p;
        float val = 0.0f;
        if (pt < NPT) {
            if (c < 3) {
                val = dirc[pt * 60 + k * 3 + c];
            } else {
                int e = c - 3, g = e / 3, i = e - g * 3;
                const short* fr = &sfeatS[(p * 20 + k) * 16 + g * 3];
                const float* Vr = Vr_s + p * 9;
                val = bf2f(fr[0]) * Vr[i * 3 + 0] + bf2f(fr[1]) * Vr[i * 3 + 1] + bf2f(fr[2]) * Vr[i * 3 + 2];
            }
        }
        concatL[(p * 20 + k) * 40 + c] = f2bf(val);
    }
    __syncthreads();

    // Phase B (swapped): H1[row][dim] = relu(concat[row]·W3[:,dim] + b3[dim])
    {
        f32x4 accB[4][4];                 // [mt: dim-tile][nt: row-tile]
#pragma unroll
        for (int mt = 0; mt < 4; ++mt)
#pragma unroll
            for (int nt = 0; nt < 4; ++nt)
#pragma unroll
                for (int r = 0; r < 4; ++r) accB[mt][nt][r] = 0.0f;

        bf16x8 aB[4], bB[4];
#pragma unroll
        for (int nt = 0; nt < 4; ++nt)    // concat fragments (per row-tile)
            aB[nt] = *(const bf16x8*)&concatL[(nt * 16 + lc) * 40 + lg * 8];
#pragma unroll
        for (int mt = 0; mt < 4; ++mt)    // W3T fragments (per dim-tile)
            bB[mt] = *(const bf16x8*)&W3T[(n0w + mt * 16 + lc) * 32 + lg * 8];
#pragma unroll
        for (int mt = 0; mt < 4; ++mt)
#pragma unroll
            for (int nt = 0; nt < 4; ++nt)
                accB[mt][nt] = __builtin_amdgcn_mfma_f32_16x16x32_bf16(bB[mt], aB[nt], accB[mt][nt], 0, 0, 0);

        // lane holds H1[row = nt*16+lc][dim = n0w + mt*16 + lg*4 + r], r=0..3
#pragma unroll
        for (int mt = 0; mt < 4; ++mt) {
            const int dim0 = n0w + mt * 16 + lg * 4;
            const float4 b3q = *(const float4*)&b3[dim0];
#pragma unroll
            for (int nt = 0; nt < 4; ++nt) {
                const int row = nt * 16 + lc;
                uint2 w;
                w.x = pack2bf(fmaxf(accB[mt][nt][0] + b3q.x, 0.0f),
                              fmaxf(accB[mt][nt][1] + b3q.y, 0.0f));
                w.y = pack2bf(fmaxf(accB[mt][nt][2] + b3q.z, 0.0f),
                              fmaxf(accB[mt][nt][3] + b3q.w, 0.0f));
                *reinterpret_cast<uint2*>(&H1L[row * 256 + (dim0 ^ swz)]) = w;
            }
        }
    }
    __syncthreads();

    // Phase C: h2 = H1 @ W4 over 8 K-chunks of 32
    f32x4 acc[4][4];
#pragma unroll
    for (int mt = 0; mt < 4; ++mt)
#pragma unroll
        for (int nt = 0; nt < 4; ++nt)
#pragma unroll
            for (int r = 0; r < 4; ++r) acc[mt][nt][r] = 0.0f;

#pragma unroll
    for (int ch = 0; ch < 8; ++ch) {
        bf16x8 a[4], b[4];
#pragma unroll
        for (int mt = 0; mt < 4; ++mt)    // H1 A-frag: row mt*16+lc, k-dims
            a[mt] = *(const bf16x8*)&H1L[(mt * 16 + lc) * 256 + ((ch * 32 + lg * 8) ^ swz)];
#pragma unroll
        for (int nt = 0; nt < 4; ++nt)
            b[nt] = *(const bf16x8*)&W4T[(n0w + nt * 16 + lc) * 256 + ch * 32 + lg * 8];
#pragma unroll
        for (int mt = 0; mt < 4; ++mt)
#pragma unroll
            for (int nt = 0; nt < 4; ++nt)
                acc[mt][nt] = __builtin_amdgcn_mfma_f32_16x16x32_bf16(a[mt], b[nt], acc[mt][nt], 0, 0, 0);
    }

    // Epilogue: relu(+b4), per-point sums via compile-time lane-group masks.
    // mt=0: rows 0-15 -> p0 | mt=1: lg0 -> p0, else p1 | mt=2: lg<2 -> p1,
    // else p2 | mt=3: lg<3 -> p2, lg3 = pad.
    const float m1 = (lg == 0) ? 1.0f : 0.0f;
    const float m2 = (lg <  2) ? 1.0f : 0.0f;
    const float m3 = (lg <  3) ? 1.0f : 0.0f;
    const int v0 = (pt0 + 0) < NPT, v1 = (pt0 + 1) < NPT, v2 = (pt0 + 2) < NPT;
#pragma unroll
    for (int nt = 0; nt < 4; ++nt) {
        int col = n0w + nt * 16 + lc;
        float b4v = b4[col];
        float a0 = 0.0f, a1 = 0.0f, a2 = 0.0f, a3 = 0.0f;
#pragma unroll
        for (int r = 0; r < 4; ++r) {
            a0 += fmaxf(acc[0][nt][r] + b4v, 0.0f);
            a1 += fmaxf(acc[1][nt][r] + b4v, 0.0f);
            a2 += fmaxf(acc[2][nt][r] + b4v, 0.0f);
            a3 += fmaxf(acc[3][nt][r] + b4v, 0.0f);
        }
        float s0 = a0 + m1 * a1;
        float s1 = (1.0f - m1) * a1 + m2 * a2;
        float s2 = (1.0f - m2) * a2 + m3 * a3;
        s0 += __shfl_xor(s0, 16); s0 += __shfl_xor(s0, 32);
        s1 += __shfl_xor(s1, 16); s1 += __shfl_xor(s1, 32);
        s2 += __shfl_xor(s2, 16); s2 += __shfl_xor(s2, 32);
        if (l < 16) {
            if (v0) pf[(pt0 + 0) * 256 + col] = s0;
            if (v1) pf[(pt0 + 1) * 256 + col] = s1;
            if (v2) pf[(pt0 + 2) * 256 + col] = s2;
        }
    }
}

// ---------------------------------------------------------------------------
// Kernel 4a: partial sum over P: 512 blocks (16 batches x 32 slices of 32).
// ---------------------------------------------------------------------------
__global__ __launch_bounds__(256) void psum_k(const float* __restrict__ pf,
                                              float* __restrict__ partial)
{
    const int t   = threadIdx.x;
    const int blk = blockIdx.x;
    const int b   = blk >> 5, sl = blk & 31;
    const float* basep = pf + ((size_t)b * NP + sl * 32) * 256 + t;
    float s = 0.0f;
#pragma unroll 8
    for (int p = 0; p < 32; ++p) s += basep[p * 256];
    partial[blk * 256 + t] = s;
}

// ---------------------------------------------------------------------------
// Kernel 4b: head proper (16 blocks).
// ---------------------------------------------------------------------------
__global__ __launch_bounds__(256) void head2_k(const float* __restrict__ partial,
                                               const float* __restrict__ Wn1,
                                               const float* __restrict__ bn1,
                                               const float* __restrict__ Wn2,
                                               const float* __restrict__ bn2,
                                               float* __restrict__ out)
{
    __shared__ float ysh[256], y1h[256], zsh[64];
    const int t = threadIdx.x, b = blockIdx.x;

    float s = 0.0f;
#pragma unroll
    for (int sl = 0; sl < 32; ++sl) s += partial[(b * 32 + sl) * 256 + t];
    ysh[t] = s * (1.0f / 1024.0f);
    __syncthreads();

    float acc = bn1[t];
    for (int c = 0; c < 256; ++c) acc += ysh[c] * Wn1[c * 256 + t];
    y1h[t] = (acc > 0.0f) ? acc : expm1f(acc);
    __syncthreads();

    if (t < NCLS) {
        float z = bn2[t];
        for (int c = 0; c < 256; ++c) z += y1h[c] * Wn2[c * NCLS + t];
        zsh[t] = z;
    }
    __syncthreads();

    if (t < 64) {
        float v = (t < NCLS) ? zsh[t] : -3.0e38f;
        float m = v;
#pragma unroll
        for (int off = 32; off >= 1; off >>= 1) m = fmaxf(m, __shfl_xor(m, off));
        float e = (t < NCLS) ? expf(zsh[t] - m) : 0.0f;
#pragma unroll
        for (int off = 32; off >= 1; off >>= 1) e += __shfl_xor(e, off);
        if (t < NCLS) out[b * NCLS + t] = zsh[t] - m - logf(e);
    }
}

// ---------------------------------------------------------------------------
extern "C" void kernel_launch(void* const* d_in, const int* in_sizes, int n_in,
                              void* d_out, int out_size, void* d_ws, size_t ws_size,
                              hipStream_t stream)
{
    const float* pos = (const float*)d_in[0];
    const float* W1  = (const float*)d_in[1];
    const float* b1  = (const float*)d_in[2];
    const float* W2  = (const float*)d_in[3];
    const float* b2  = (const float*)d_in[4];
    const float* W3  = (const float*)d_in[5];
    const float* b3  = (const float*)d_in[6];
    const float* W4  = (const float*)d_in[7];
    const float* b4  = (const float*)d_in[8];
    const float* Wn1 = (const float*)d_in[9];
    const float* bn1 = (const float*)d_in[10];
    const float* Wn2 = (const float*)d_in[11];
    const float* bn2 = (const float*)d_in[12];
    float* out = (float*)d_out;

    char* ws = (char*)d_ws;
    // workspace layout (bytes) — R8 layout
    int*   nbr     = (int*)(ws + 0);               //  1,310,720
    float* dirc    = (float*)(ws + 1310720);       //  3,932,160
    short* feat    = (short*)(ws + 5242880);       //    491,520 (bf16)
    float* Vg      = (float*)(ws + 6225920);       //    589,824
    float* pf      = (float*)(ws + 6815744);       // 16,777,216
    short* W4T     = (short*)(ws + 23592960);      //    131,072
    short* W3T     = (short*)(ws + 23724032);      //     16,384
    float* partial = (float*)(ws + 5242880);       // reuses feat region after mlp_k (524,288 B)

    prep_k <<<256,            256, 0, stream>>>(W3, W4, W3T, W4T);
    knn_k  <<<1024,           256, 0, stream>>>(pos, nbr);
    geom_k <<<256,             64, 0, stream>>>(pos, nbr, W1, b1, W2, b2, dirc, feat, Vg);
    mlp_k  <<<(NPT + 2) / 3,  256, 0, stream>>>(nbr, dirc, feat, Vg, W3T, b3, W4T, b4, pf);
    psum_k <<<512,            256, 0, stream>>>(pf, partial);
    head2_k<<<NB,             256, 0, stream>>>(partial, Wn1, bn1, Wn2, bn2, out);
}